// Round 7
// baseline (273.935 us; speedup 1.0000x reference)
//
#include <hip/hip_runtime.h>
#include <hip/hip_bf16.h>

#define Bn  512
#define DXn 128
#define Hn  512

using bf16x8 = __attribute__((ext_vector_type(8))) short;
using f32x4  = __attribute__((ext_vector_type(4))) float;

#define VMCNT(n) asm volatile("s_waitcnt vmcnt(" #n ")" ::: "memory")

// packed f32x2 -> bf16x2 (RNE); compiler emits v_cvt_pk_bf16_f32
static __device__ __forceinline__ unsigned int pkbf(float lo, float hi) {
    union { __hip_bfloat162 b; unsigned int u; } cv;
    cv.b = __float22bfloat162_rn(make_float2(lo, hi));
    return cv.u;
}

// async global->LDS, 16B per lane; LDS dest = wave-uniform base + lane*16
static __device__ __forceinline__ void gld_lds16(const void* g, void* l) {
    __builtin_amdgcn_global_load_lds(
        (const __attribute__((address_space(1))) unsigned int*)g,
        (__attribute__((address_space(3))) unsigned int*)l,
        16, 0, 0);
}

// ---------------------------------------------------------------------------
// Fused prep kernel (unchanged from R5/R6):
//  blocks 0..255   : hxb[i][h] = x·W1x^T + b1 / hyv[j][h] = y·W1y^T
//  blocks 256..383 : W2 f32 -> bf16 step-major fragment layout:
//     w2s[s 16][c 32][lane 64][8], elem = W2[c*16 + (l&15)][s*32 + (l>>4)*8 + j]
// ---------------------------------------------------------------------------
__global__ __launch_bounds__(256) void prep_fused(
    const float* __restrict__ x, const float* __restrict__ y,
    const float* __restrict__ W1, const float* __restrict__ b1,
    const float* __restrict__ W2,
    float* __restrict__ hxb, float* __restrict__ hyv,
    unsigned short* __restrict__ w2s)
{
    const int bid = blockIdx.x;
    const int t = threadIdx.x;

    if (bid >= 256) {
        const int T = (bid - 256) * 256 + t;        // 0 .. 32767
        const int l = T & 63;
        const int c = (T >> 6) & 31;
        const int s = T >> 11;
        const int row = c * 16 + (l & 15);
        const int col = s * 32 + (l >> 4) * 8;
        const float* p = &W2[row * Hn + col];
        const float4 v0 = *(const float4*)p;
        const float4 v1 = *(const float4*)(p + 4);
        uint4 pk;
        pk.x = pkbf(v0.x, v0.y);
        pk.y = pkbf(v0.z, v0.w);
        pk.z = pkbf(v1.x, v1.y);
        pk.w = pkbf(v1.z, v1.w);
        *(uint4*)(w2s + (size_t)T * 8) = pk;        // T*8 == ((s*32+c)*64+l)*8
        return;
    }

    // ---- first-layer GEMM: 32 i x 64 h per block, 8 outputs/thread ----
    const int which = bid >> 7;
    const int rem = bid & 127;
    const int i0 = (rem >> 3) * 32;
    const int h0 = (rem & 7) * 64;
    const float* __restrict__ src = which ? y : x;
    float* __restrict__ dst = which ? hyv : hxb;
    const int off = which ? DXn : 0;

    __shared__ float xs[32][132];
    __shared__ float ws[64][132];
    #pragma unroll
    for (int it = 0; it < 4; ++it) {
        const int fi = it * 256 + t;
        const int r = fi >> 5, q = fi & 31;
        *(float4*)&xs[r][q * 4] = *(const float4*)&src[(i0 + r) * DXn + q * 4];
    }
    #pragma unroll
    for (int it = 0; it < 8; ++it) {
        const int fi = it * 256 + t;
        const int r = fi >> 5, q = fi & 31;
        *(float4*)&ws[r][q * 4] = *(const float4*)&W1[(h0 + r) * (2 * DXn) + off + q * 4];
    }
    __syncthreads();

    const int tx = t & 15;
    const int ty = t >> 4;
    float acc[2][4];
    #pragma unroll
    for (int v = 0; v < 2; ++v)
        #pragma unroll
        for (int u = 0; u < 4; ++u)
            acc[v][u] = which ? 0.0f : b1[h0 + tx + u * 16];

    #pragma unroll 4
    for (int c4 = 0; c4 < 32; ++c4) {
        const float4 xv0 = *(const float4*)&xs[ty * 2 + 0][c4 * 4];
        const float4 xv1 = *(const float4*)&xs[ty * 2 + 1][c4 * 4];
        #pragma unroll
        for (int u = 0; u < 4; ++u) {
            const float4 wv = *(const float4*)&ws[tx + u * 16][c4 * 4];
            acc[0][u] = fmaf(xv0.x, wv.x, fmaf(xv0.y, wv.y, fmaf(xv0.z, wv.z, fmaf(xv0.w, wv.w, acc[0][u]))));
            acc[1][u] = fmaf(xv1.x, wv.x, fmaf(xv1.y, wv.y, fmaf(xv1.z, wv.z, fmaf(xv1.w, wv.w, acc[1][u]))));
        }
    }
    #pragma unroll
    for (int v = 0; v < 2; ++v)
        #pragma unroll
        for (int u = 0; u < 4; ++u)
            dst[(size_t)(i0 + ty * 2 + v) * Hn + h0 + tx + u * 16] = acc[v][u];
}

// ---------------------------------------------------------------------------
// Main fused kernel — m201-style barrier-paced 2-phase K-tiles, counted vmcnt.
// Block = (one i, 128 j's), 8 waves, wave tile 128x64 (fi=8, fj=4), 16x16x32.
// 16 K-tiles of BK=32 (one MFMA K-step each).
// LDS (80KB): A dbuf 2x8KB (reg-staged: A computed = relu(hx+hy), ds_write,
//             barrier-paced), B dbuf 2x32KB (global_load_lds, WAVE-PRIVATE
//             chunks: stager==reader -> counted vmcnt only, no barrier dep).
// Per K-tile t:
//  phase alpha: [issue A-vmem(t+1) f32 loads; issue 4 gld_lds B(t+1)]
//               VMCNT(8) retires B(t);  ds_read b[4],a[0..3];
//               s_barrier; MFMA x16 (fi0-3) in setprio(1); s_barrier
//  phase beta : ds_read a[4..7]; cvt+ds_write A(t+1);
//               MFMA x16 (fi4-7) in setprio(1);
//               lgkmcnt(0) (A-write visible); s_barrier
// vmcnt ledger (in-order): [B(t)x4] [A-vmem(t+1)x4] [B(t+1)x4] -> wait 8;
// compiler's wait for A-vmem f32 regs in beta retires A, leaves B(t+1) flying.
// Never drains vmcnt in steady state (the m218 lever).
// ---------------------------------------------------------------------------
__global__ __launch_bounds__(512, 2) void critic_main(
    const float* __restrict__ hxb, const float* __restrict__ hyv,
    const unsigned short* __restrict__ w2s, const float* __restrict__ b2,
    const float* __restrict__ W3, const float* __restrict__ b3,
    float* __restrict__ out)
{
    __shared__ __align__(16) unsigned char smem[81920];
    // A dbuf: [2][8 fi][64 lane][16B] at 0, 16KB total
    // B dbuf: [2][32 c][64 lane][16B] at 16384, 64KB total
    float* red = (float*)smem;                      // epilogue reuse

    const int i   = blockIdx.y;
    const int j0  = blockIdx.x * 128;
    const int tid = threadIdx.x;
    const int w   = tid >> 6;
    const int l   = tid & 63;
    const int lg  = l >> 4;
    const int lm  = l & 15;

    const float* __restrict__ hxrow = &hxb[(size_t)i * Hn];
    const float* __restrict__ hyrow = &hyv[(size_t)(j0 + w * 16 + lm) * Hn];
    const unsigned char* __restrict__ w2b = (const unsigned char*)w2s;

    // ---- prologue: A-vmem(0) -> cvt -> ds_write A(0); gld B(0) ----
    {
        const int hb = lg * 8;                      // tile 0
        const float4 sy0 = *(const float4*)(hyrow + hb);
        const float4 sy1 = *(const float4*)(hyrow + hb + 4);
        const float4 sx0 = *(const float4*)(hxrow + hb);
        const float4 sx1 = *(const float4*)(hxrow + hb + 4);
        #pragma unroll
        for (int n = 0; n < 4; ++n) {
            const int c = w * 4 + n;
            gld_lds16(w2b + (size_t)c * 1024 + l * 16,
                      smem + 16384 + c * 1024);
        }
        uint4 pk;
        pk.x = pkbf(fmaxf(sy0.x + sx0.x, 0.f), fmaxf(sy0.y + sx0.y, 0.f));
        pk.y = pkbf(fmaxf(sy0.z + sx0.z, 0.f), fmaxf(sy0.w + sx0.w, 0.f));
        pk.z = pkbf(fmaxf(sy1.x + sx1.x, 0.f), fmaxf(sy1.y + sx1.y, 0.f));
        pk.w = pkbf(fmaxf(sy1.z + sx1.z, 0.f), fmaxf(sy1.w + sx1.w, 0.f));
        *(uint4*)(smem + (w * 64 + l) * 16) = pk;
        asm volatile("s_waitcnt lgkmcnt(0)" ::: "memory");
        __builtin_amdgcn_sched_barrier(0);
        __builtin_amdgcn_s_barrier();
    }

    f32x4 acc[8][4] = {};

    #pragma unroll
    for (int t = 0; t < 16; ++t) {
        const int ct = t & 1;
        const unsigned short* ab = (const unsigned short*)(smem + ct * 8192);
        const unsigned char*  bb = smem + 16384 + ct * 32768;
        unsigned short* abn = (unsigned short*)(smem + (ct ^ 1) * 8192);
        unsigned char*  bbn = smem + 16384 + (ct ^ 1) * 32768;

        // ================= phase alpha =================
        float4 sy0, sy1, sx0, sx1;
        if (t < 15) {
            const int hb = (t + 1) * 32 + lg * 8;
            sy0 = *(const float4*)(hyrow + hb);        // A-vmem(t+1): issued
            sy1 = *(const float4*)(hyrow + hb + 4);    //   BEFORE B-gld so the
            sx0 = *(const float4*)(hxrow + hb);        //   compiler's wait for
            sx1 = *(const float4*)(hxrow + hb + 4);    //   them leaves B flying
            #pragma unroll
            for (int n = 0; n < 4; ++n) {
                const int c = w * 4 + n;
                gld_lds16(w2b + (size_t)(t + 1) * 32768 + c * 1024 + l * 16,
                          bbn + c * 1024);
            }
        }
        if (t < 15) { VMCNT(8); } else { VMCNT(0); }   // retire B(t) only

        bf16x8 b[4], a0[4];
        #pragma unroll
        for (int fj = 0; fj < 4; ++fj)
            b[fj] = *(const bf16x8*)(bb + (w * 4 + fj) * 1024 + l * 16);
        #pragma unroll
        for (int fi = 0; fi < 4; ++fi)
            a0[fi] = *(const bf16x8*)(ab + ((size_t)fi * 64 + l) * 8);

        __builtin_amdgcn_s_barrier();    // pace: all waves issued their reads
        __builtin_amdgcn_s_setprio(1);
        #pragma unroll
        for (int fi = 0; fi < 4; ++fi)
            #pragma unroll
            for (int fj = 0; fj < 4; ++fj)
                acc[fi][fj] = __builtin_amdgcn_mfma_f32_16x16x32_bf16(
                    a0[fi], b[fj], acc[fi][fj], 0, 0, 0);
        __builtin_amdgcn_s_setprio(0);
        __builtin_amdgcn_s_barrier();

        // ================= phase beta =================
        bf16x8 a1[4];
        #pragma unroll
        for (int fi = 0; fi < 4; ++fi)
            a1[fi] = *(const bf16x8*)(ab + ((size_t)(fi + 4) * 64 + l) * 8);
        if (t < 15) {                                  // cvt + ds_write A(t+1)
            uint4 pk;
            pk.x = pkbf(fmaxf(sy0.x + sx0.x, 0.f), fmaxf(sy0.y + sx0.y, 0.f));
            pk.y = pkbf(fmaxf(sy0.z + sx0.z, 0.f), fmaxf(sy0.w + sx0.w, 0.f));
            pk.z = pkbf(fmaxf(sy1.x + sx1.x, 0.f), fmaxf(sy1.y + sx1.y, 0.f));
            pk.w = pkbf(fmaxf(sy1.z + sx1.z, 0.f), fmaxf(sy1.w + sx1.w, 0.f));
            *(uint4*)((unsigned char*)abn + (w * 64 + l) * 16) = pk;
        }
        __builtin_amdgcn_s_setprio(1);
        #pragma unroll
        for (int fi = 0; fi < 4; ++fi)
            #pragma unroll
            for (int fj = 0; fj < 4; ++fj)
                acc[fi + 4][fj] = __builtin_amdgcn_mfma_f32_16x16x32_bf16(
                    a1[fi], b[fj], acc[fi + 4][fj], 0, 0, 0);
        __builtin_amdgcn_s_setprio(0);
        asm volatile("s_waitcnt lgkmcnt(0)" ::: "memory");  // A-write in LDS
        __builtin_amdgcn_sched_barrier(0);
        __builtin_amdgcn_s_barrier();
    }

    // ---- epilogue: relu(C + b2)*W3, reduce over k ----
    float b2v[4], w3v[4];
    #pragma unroll
    for (int fj = 0; fj < 4; ++fj) {
        const int k = w * 64 + fj * 16 + lm;
        b2v[fj] = b2[k];
        w3v[fj] = W3[k];
    }
    float rp[8][4];
    #pragma unroll
    for (int fi = 0; fi < 8; ++fi) {
        #pragma unroll
        for (int qq = 0; qq < 4; ++qq) {
            float ssum = 0.f;
            #pragma unroll
            for (int fj = 0; fj < 4; ++fj) {
                float c = acc[fi][fj][qq] + b2v[fj];
                c = fmaxf(c, 0.f);
                ssum = fmaf(c, w3v[fj], ssum);
            }
            rp[fi][qq] = ssum;
        }
    }
    #pragma unroll
    for (int m = 1; m < 16; m <<= 1) {
        #pragma unroll
        for (int fi = 0; fi < 8; ++fi)
            #pragma unroll
            for (int qq = 0; qq < 4; ++qq)
                rp[fi][qq] += __shfl_xor(rp[fi][qq], m, 64);
    }

    __syncthreads();   // all LDS work done; safe to reuse smem as red[]
    if (lm == 0) {
        #pragma unroll
        for (int fi = 0; fi < 8; ++fi)
            #pragma unroll
            for (int qq = 0; qq < 4; ++qq)
                red[w * 128 + fi * 16 + lg * 4 + qq] = rp[fi][qq];
    }
    __syncthreads();
    if (tid < 128) {
        float ssum = 0.f;
        #pragma unroll
        for (int ww = 0; ww < 8; ++ww) ssum += red[ww * 128 + tid];
        out[(size_t)i * Bn + j0 + tid] = ssum + b3[0];
    }
}

// ---------------------------------------------------------------------------
extern "C" void kernel_launch(void* const* d_in, const int* in_sizes, int n_in,
                              void* d_out, int out_size, void* d_ws, size_t ws_size,
                              hipStream_t stream) {
    const float* x  = (const float*)d_in[0];
    const float* y  = (const float*)d_in[1];
    const float* W1 = (const float*)d_in[2];
    const float* b1 = (const float*)d_in[3];
    const float* W2 = (const float*)d_in[4];
    const float* b2 = (const float*)d_in[5];
    const float* W3 = (const float*)d_in[6];
    const float* b3 = (const float*)d_in[7];
    float* out = (float*)d_out;

    char* ws = (char*)d_ws;
    float* hxb = (float*)ws;                                   // 1 MB
    float* hyv = (float*)(ws + (size_t)Bn * Hn * 4);           // 1 MB
    unsigned short* w2s = (unsigned short*)(ws + (size_t)2 * Bn * Hn * 4); // 512 KB

    prep_fused<<<dim3(384), dim3(256), 0, stream>>>(x, y, W1, b1, W2, hxb, hyv, w2s);
    critic_main<<<dim3(Bn / 128, Bn), dim3(512), 0, stream>>>(hxb, hyv, w2s, b2, W3, b3, out);
}